// Round 2
// baseline (89.322 us; speedup 1.0000x reference)
//
#include <hip/hip_runtime.h>

#define IMG_H 224
#define IMG_W 224
#define NPIX (IMG_H * IMG_W)        // 50176
#define NG 1024
#define SPLIT 8
#define GPS (NG / SPLIT)            // 128 gaussians per slice
#define TPB 256
#define PPT 2                       // pixels per thread (same row, x-adjacent)
#define PIX_PER_BLK (TPB * PPT)     // 512
#define NBLK_X (NPIX / PIX_PER_BLK) // 98 exact

#define ELIM -21.640425613334451f   // 30 * (-0.5*log2(e))  -> min(dist,30)

struct __align__(16) GParam {
    float cx, cy, A, B, C, cr, cg, cb;
};

// ---------- pass 1: per-gaussian parameter prep (runs once, 1024 threads) ----------
__global__ __launch_bounds__(256) void prep_kernel(
    const float* __restrict__ alpha,
    const float* __restrict__ color,
    const float* __restrict__ offset,
    const float* __restrict__ scale,
    const float* __restrict__ rotation,
    const float* __restrict__ basep,
    const float* __restrict__ iw,
    GParam* __restrict__ gp)
{
    const int g = blockIdx.x * 256 + threadIdx.x;
    if (g >= NG) return;
    float cx = fminf(fmaxf(basep[2*g]   + offset[2*g],   0.f), 224.f);
    float cy = fminf(fmaxf(basep[2*g+1] + offset[2*g+1], 0.f), 224.f);
    float cr_ = cosf(rotation[g]);
    float sr_ = sinf(rotation[g]);
    float s1q = scale[2*g]   * scale[2*g];
    float s2q = scale[2*g+1] * scale[2*g+1];
    float c00 = cr_*cr_*s1q + sr_*sr_*s2q + 1e-4f;
    float c01 = cr_*sr_*(s1q - s2q);
    float c11 = sr_*sr_*s1q + cr_*cr_*s2q + 1e-4f;
    float rdet = 1.0f / (c00*c11 - c01*c01);
    const float k = -0.72134752044448170368f;   // -0.5 * log2(e)
    GParam q;
    q.cx = cx; q.cy = cy;
    q.A =  k * c11 * rdet;            // k * inv00
    q.B = -2.0f * k * c01 * rdet;     // 2k * inv01
    q.C =  k * c00 * rdet;            // k * inv11
    float a = alpha[g] * iw[g];
    q.cr = a * color[3*g];
    q.cg = a * color[3*g+1];
    q.cb = a * color[3*g+2];
    gp[g] = q;
}

// ---------- pass 2: rasterize (params via wave-uniform scalar loads) ----------
__global__ __launch_bounds__(256) void raster_kernel(
    const GParam* __restrict__ gp,
    float* __restrict__ out)
{
    const int tid = threadIdx.x;
    const int p0  = blockIdx.x * PIX_PER_BLK + tid * 2;  // even; p0,p0+1 same row
    const float px = (float)(p0 % IMG_W);
    const float py = (float)(p0 / IMG_W);
    const GParam* __restrict__ gs = gp + blockIdx.y * GPS;

    float r0 = 0.f, g0 = 0.f, b0 = 0.f;
    float r1 = 0.f, g1 = 0.f, b1 = 0.f;

    #pragma unroll 4
    for (int i = 0; i < GPS; ++i) {
        const float A  = gs[i].A;
        const float Bc = gs[i].B;
        const float Cc = gs[i].C;
        float dy  = py - gs[i].cy;
        float t   = Bc * dy;              // B*dy (shared)
        float w2  = Cc * (dy * dy);       // C*dy^2 (shared)
        float dx0 = px - gs[i].cx;
        float u0  = fmaf(A, dx0, t);
        float e0  = fmaf(dx0, u0, w2);
        float dx1 = dx0 + 1.0f;
        float u1  = u0 + A;               // A*dx1 + t
        float e1  = fmaf(dx1, u1, w2);
        e0 = fmaxf(e0, ELIM);
        e1 = fmaxf(e1, ELIM);
        float w0 = __builtin_amdgcn_exp2f(e0);
        float w1 = __builtin_amdgcn_exp2f(e1);
        const float cr = gs[i].cr, cg = gs[i].cg, cb = gs[i].cb;
        r0 = fmaf(w0, cr, r0);  r1 = fmaf(w1, cr, r1);
        g0 = fmaf(w0, cg, g0);  g1 = fmaf(w1, cg, g1);
        b0 = fmaf(w0, cb, b0);  b1 = fmaf(w1, cb, b1);
    }

    atomicAdd(&out[p0],            r0);  atomicAdd(&out[p0 + 1],            r1);
    atomicAdd(&out[NPIX + p0],     g0);  atomicAdd(&out[NPIX + p0 + 1],     g1);
    atomicAdd(&out[2*NPIX + p0],   b0);  atomicAdd(&out[2*NPIX + p0 + 1],   b1);
}

// ---------- fallback (self-contained, LDS params) if ws too small ----------
__global__ __launch_bounds__(256) void raster_lds_kernel(
    const float* __restrict__ alpha,
    const float* __restrict__ color,
    const float* __restrict__ offset,
    const float* __restrict__ scale,
    const float* __restrict__ rotation,
    const float* __restrict__ basep,
    const float* __restrict__ iw,
    float* __restrict__ out)
{
    __shared__ GParam gp[GPS];
    const int tid = threadIdx.x;
    if (tid < GPS) {
        const int g = blockIdx.y * GPS + tid;
        float cx = fminf(fmaxf(basep[2*g]   + offset[2*g],   0.f), 224.f);
        float cy = fminf(fmaxf(basep[2*g+1] + offset[2*g+1], 0.f), 224.f);
        float cr_ = cosf(rotation[g]);
        float sr_ = sinf(rotation[g]);
        float s1q = scale[2*g]   * scale[2*g];
        float s2q = scale[2*g+1] * scale[2*g+1];
        float c00 = cr_*cr_*s1q + sr_*sr_*s2q + 1e-4f;
        float c01 = cr_*sr_*(s1q - s2q);
        float c11 = sr_*sr_*s1q + cr_*cr_*s2q + 1e-4f;
        float rdet = 1.0f / (c00*c11 - c01*c01);
        const float k = -0.72134752044448170368f;
        GParam q;
        q.cx = cx; q.cy = cy;
        q.A =  k * c11 * rdet;
        q.B = -2.0f * k * c01 * rdet;
        q.C =  k * c00 * rdet;
        float a = alpha[g] * iw[g];
        q.cr = a * color[3*g];
        q.cg = a * color[3*g+1];
        q.cb = a * color[3*g+2];
        gp[tid] = q;
    }
    __syncthreads();

    const int p = blockIdx.x * 256 + tid;
    const float px = (float)(p % IMG_W);
    const float py = (float)(p / IMG_W);
    float r = 0.f, g = 0.f, b = 0.f;
    #pragma unroll 4
    for (int i = 0; i < GPS; ++i) {
        GParam q = gp[i];
        float dx = px - q.cx;
        float dy = py - q.cy;
        float e = fmaf(dx, fmaf(q.A, dx, q.B * dy), q.C * (dy * dy));
        e = fmaxf(e, ELIM);
        float w = __builtin_amdgcn_exp2f(e);
        r = fmaf(w, q.cr, r);
        g = fmaf(w, q.cg, g);
        b = fmaf(w, q.cb, b);
    }
    atomicAdd(&out[p],          r);
    atomicAdd(&out[NPIX + p],   g);
    atomicAdd(&out[2*NPIX + p], b);
}

extern "C" void kernel_launch(void* const* d_in, const int* in_sizes, int n_in,
                              void* d_out, int out_size, void* d_ws, size_t ws_size,
                              hipStream_t stream)
{
    const float* alpha    = (const float*)d_in[0];
    const float* color    = (const float*)d_in[1];
    const float* offset   = (const float*)d_in[2];
    const float* scale    = (const float*)d_in[3];
    const float* rotation = (const float*)d_in[4];
    const float* basep    = (const float*)d_in[5];
    const float* iw       = (const float*)d_in[6];
    float* out = (float*)d_out;

    hipMemsetAsync(out, 0, (size_t)out_size * sizeof(float), stream);

    if (ws_size >= sizeof(GParam) * NG) {
        GParam* gp = (GParam*)d_ws;
        prep_kernel<<<(NG + 255) / 256, 256, 0, stream>>>(
            alpha, color, offset, scale, rotation, basep, iw, gp);
        dim3 grid(NBLK_X, SPLIT);
        raster_kernel<<<grid, TPB, 0, stream>>>(gp, out);
    } else {
        dim3 grid(NPIX / 256, SPLIT);
        raster_lds_kernel<<<grid, 256, 0, stream>>>(
            alpha, color, offset, scale, rotation, basep, iw, out);
    }
}